// Round 16
// baseline (189.201 us; speedup 1.0000x reference)
//
#include <hip/hip_runtime.h>
#include <hip/hip_bf16.h>
#include <cstddef>

typedef __hip_bfloat16 bf16;
typedef __attribute__((ext_vector_type(8))) short bf16x8;   // MFMA A/B frag
typedef __attribute__((ext_vector_type(4))) float f32x4;    // MFMA C/D frag
typedef __attribute__((ext_vector_type(4))) short short4v;  // 4x bf16 packed

__device__ __forceinline__ float b2f(bf16 v) { return __bfloat162float(v); }
__device__ __forceinline__ bf16 f2b(float v) { return __float2bfloat16(v); }

#define MFMA(a, b, c) __builtin_amdgcn_mfma_f32_16x16x32_bf16((a), (b), (c), 0, 0, 0)

// Weight layout inside wb (bf16): Wq [0,64K), Wkv [64K,192K), Wp [192K,256K),
// Wsr permuted [256K,512K) with k' = p*256 + c  (p = kh*2+kw).
#define WQ_OFF   0
#define WKV_OFF  65536
#define WP_OFF   196608
#define WSR_OFF  262144

// ---------------------------------------------------------------------------
// Prepass A: x0|x1 fp32 -> xb bf16 (16384 x 256 rows = a*8192 + b*4096 + n).
// ---------------------------------------------------------------------------
__global__ __launch_bounds__(256) void cvt_x(
    const float* __restrict__ x0, const float* __restrict__ x1,
    bf16* __restrict__ xb) {
  const int gid = blockIdx.x * 256 + threadIdx.x;   // 262144 threads
  for (int i = gid; i < 1048576; i += 262144) {     // float4 units
    const float4 v = (i < 524288) ? ((const float4*)x0)[i]
                                  : ((const float4*)x1)[i - 524288];
    union { bf16 h[4]; short4v s; } u;
    u.h[0] = f2b(v.x); u.h[1] = f2b(v.y); u.h[2] = f2b(v.z); u.h[3] = f2b(v.w);
    ((short4v*)xb)[i] = u.s;
  }
}

// ---------------------------------------------------------------------------
// Prepass B: weights fp32 -> wb bf16 (Wsr with the p-major k permutation).
// ---------------------------------------------------------------------------
__global__ __launch_bounds__(256) void cvt_w(
    const float* __restrict__ Wq, const float* __restrict__ Wkv,
    const float* __restrict__ Wp, const float* __restrict__ Wsr,
    bf16* __restrict__ wb) {
  const int gid = blockIdx.x * 256 + threadIdx.x;   // 131072 threads
  for (int i = gid; i < 524288; i += 131072) {
    float v;
    if (i < WKV_OFF)       v = Wq[i];
    else if (i < WP_OFF)   v = Wkv[i - WKV_OFF];
    else if (i < WSR_OFF)  v = Wp[i - WP_OFF];
    else {
      const int r = i - WSR_OFF;
      const int o = r >> 10, k = r & 1023;
      const int p = k >> 8, c = k & 255;
      v = Wsr[o * 1024 + c * 4 + p];
    }
    wb[i] = f2b(v);
  }
}

// ===========================================================================
// Full-width GEMM core: block = 64 rows x 256 cols, 4 waves (16 rows each).
// W streamed per 32-k step into frag-linear LDS (slot = (col*4+quad)*8),
// double-buffered, one barrier/step. A loaded once (1 frag/step/wave).
// Thread t stages chunk c = t + 256*u: global (colbase + (c>>2))*ldw + k0 +
// (c&3)*8 -> LDS slot c*8. acc[j] covers cols j*16+l16.
// ===========================================================================
#define GEMM256_BODY(APTR, WBASE, LDW)                                       \
  bf16x8 wpre[4];                                                            \
  _Pragma("unroll")                                                          \
  for (int u = 0; u < 4; ++u) {                                              \
    const int c = t + 256 * u;                                               \
    wpre[u] = *(const bf16x8*)((WBASE) + (c >> 2) * (LDW) + (c & 3) * 8);    \
  }                                                                          \
  _Pragma("unroll")                                                          \
  for (int u = 0; u < 4; ++u)                                                \
    *(bf16x8*)&Wl[0][(t + 256 * u) * 8] = wpre[u];                           \
  __syncthreads();                                                           \
  f32x4 acc[16];                                                             \
  _Pragma("unroll")                                                          \
  for (int j = 0; j < 16; ++j) acc[j] = (f32x4){0.f, 0.f, 0.f, 0.f};         \
  for (int k = 0; k < 8; ++k) {                                              \
    const int cur = k & 1;                                                   \
    if (k < 7) {                                                             \
      _Pragma("unroll")                                                      \
      for (int u = 0; u < 4; ++u) {                                          \
        const int c = t + 256 * u;                                           \
        wpre[u] = *(const bf16x8*)((WBASE) + (c >> 2) * (LDW) +              \
                                   (k + 1) * 32 + (c & 3) * 8);              \
      }                                                                      \
    }                                                                        \
    const bf16x8 af = *(const bf16x8*)((APTR) + k * 32);                     \
    _Pragma("unroll")                                                        \
    for (int j = 0; j < 16; ++j) {                                           \
      const bf16x8 wf =                                                      \
          *(const bf16x8*)&Wl[cur][(j * 64 + l16 * 4 + quad) * 8];           \
      acc[j] = MFMA(af, wf, acc[j]);                                         \
    }                                                                        \
    if (k < 7) {                                                             \
      _Pragma("unroll")                                                      \
      for (int u = 0; u < 4; ++u)                                            \
        *(bf16x8*)&Wl[cur ^ 1][(t + 256 * u) * 8] = wpre[u];                 \
    }                                                                        \
    __syncthreads();                                                         \
  }

// ---------------------------------------------------------------------------
// Kernel 1: q = (xb @ Wq^T) * scale -> bf16 (d_out staging). grid 256.
// ---------------------------------------------------------------------------
__global__ __launch_bounds__(256) void qproj_mfma(
    const bf16* __restrict__ xb, const bf16* __restrict__ wb,
    bf16* __restrict__ q) {
  __shared__ bf16 Wl[2][8192];   // 32 KB, frag-linear
  const int t = threadIdx.x;
  const int wave = t >> 6, lane = t & 63, quad = lane >> 4, l16 = lane & 15;
  const int row0 = blockIdx.x * 64 + wave * 16;
  const bf16* ap = xb + (row0 + l16) * 256 + quad * 8;
  const bf16* wbase = wb + WQ_OFF;
  GEMM256_BODY(ap, wbase, 256);
  const float scale = 0.17677669529663687f;  // 1/sqrt(32)
  #pragma unroll
  for (int j = 0; j < 16; ++j)
    #pragma unroll
    for (int r = 0; r < 4; ++r)
      q[(row0 + quad * 4 + r) * 256 + j * 16 + l16] = f2b(acc[j][r] * scale);
}

// ---------------------------------------------------------------------------
// Kernel 2: conv as 4 p-passes of 256-K MFMA GEMM (Wsr pre-permuted).
// Unchanged from round 15 (proven). grid (32, 4).
// ---------------------------------------------------------------------------
#define STAGE_W(W_lds, wgl, ldg)                                             \
  _Pragma("unroll")                                                          \
  for (int u = 0; u < 8; ++u) {                                              \
    const int idx = u * 256 + t;                                             \
    const int wr = idx >> 5;                                                 \
    const int wc = (idx & 31) * 8;                                           \
    *(bf16x8*)&W_lds[wr][wc] = *(const bf16x8*)((wgl) + wr * (ldg) + wc);    \
  }

__global__ __launch_bounds__(256) void conv_mfma(
    const bf16* __restrict__ xb, const bf16* __restrict__ wb,
    const float* __restrict__ bsr, bf16* __restrict__ xsb) {
  __shared__ bf16 W_lds[64][264];
  const int t = threadIdx.x;
  const int wave = t >> 6, lane = t & 63, quad = lane >> 4, l16 = lane & 15;
  const int row0 = blockIdx.x * 128 + wave * 32;
  const int colh = blockIdx.y * 64;
  int ab[2], mi_[2], mj[2];
  #pragma unroll
  for (int s = 0; s < 2; ++s) {
    const int mrow = row0 + s * 16 + l16;
    ab[s] = mrow >> 10;
    const int m = mrow & 1023;
    mi_[s] = m >> 5; mj[s] = m & 31;
  }
  f32x4 acc[2][4];
  #pragma unroll
  for (int s = 0; s < 2; ++s)
    #pragma unroll
    for (int j = 0; j < 4; ++j) acc[s][j] = (f32x4){0.f, 0.f, 0.f, 0.f};
  for (int p = 0; p < 4; ++p) {
    __syncthreads();
    STAGE_W(W_lds, wb + WSR_OFF + colh * 1024 + p * 256, 1024);
    __syncthreads();
    const int n0 = (2 * mi_[0] + (p >> 1)) * 64 + 2 * mj[0] + (p & 1);
    const int n1 = (2 * mi_[1] + (p >> 1)) * 64 + 2 * mj[1] + (p & 1);
    const bf16* ap0 = xb + (ab[0] * 4096 + n0) * 256 + quad * 8;
    const bf16* ap1 = xb + (ab[1] * 4096 + n1) * 256 + quad * 8;
    #pragma unroll
    for (int c0 = 0; c0 < 256; c0 += 32) {
      const bf16x8 af0 = *(const bf16x8*)(ap0 + c0);
      const bf16x8 af1 = *(const bf16x8*)(ap1 + c0);
      #pragma unroll
      for (int j = 0; j < 4; ++j) {
        const bf16x8 wf = *(const bf16x8*)&W_lds[j * 16 + l16][c0 + quad * 8];
        acc[0][j] = MFMA(af0, wf, acc[0][j]);
        acc[1][j] = MFMA(af1, wf, acc[1][j]);
      }
    }
  }
  #pragma unroll
  for (int s = 0; s < 2; ++s)
    #pragma unroll
    for (int j = 0; j < 4; ++j) {
      const int col = colh + j * 16 + l16;
      const float bv = bsr[col];
      #pragma unroll
      for (int r = 0; r < 4; ++r)
        xsb[(row0 + s * 16 + quad * 4 + r) * 256 + col] =
            f2b(acc[s][j][r] + bv);
    }
}

// ---------------------------------------------------------------------------
// Kernel 3: layernorm over C=256, in place on xsb (bf16; math fp32).
// ---------------------------------------------------------------------------
__global__ __launch_bounds__(256) void ln_kernel(
    bf16* __restrict__ xsb,
    const float* __restrict__ w0, const float* __restrict__ b0,
    const float* __restrict__ w1, const float* __restrict__ b1) {
  const int row = blockIdx.x;  // 4096
  const int a = row >> 11;
  const int t = threadIdx.x;
  const float v = b2f(xsb[row * 256 + t]);
  __shared__ float red[4], red2[4];
  float s = v;
  #pragma unroll
  for (int off = 32; off >= 1; off >>= 1) s += __shfl_down(s, off, 64);
  if ((t & 63) == 0) red[t >> 6] = s;
  __syncthreads();
  const float mean = (red[0] + red[1] + red[2] + red[3]) * (1.0f / 256.0f);
  const float dv = v - mean;
  float s2 = dv * dv;
  #pragma unroll
  for (int off = 32; off >= 1; off >>= 1) s2 += __shfl_down(s2, off, 64);
  if ((t & 63) == 0) red2[t >> 6] = s2;
  __syncthreads();
  const float var = (red2[0] + red2[1] + red2[2] + red2[3]) * (1.0f / 256.0f);
  const float* w = a ? w1 : w0;
  const float* bbp = a ? b1 : b0;
  xsb[row * 256 + t] = f2b(dv * rsqrtf(var + 1e-5f) * w[t] + bbp[t]);
}

// ---------------------------------------------------------------------------
// Kernel 4: kv = xsb @ Wkv^T, full-width blocks. grid (64, 2): y=0 -> K cols
// [0,256) -> kbuf [abh][m][d]; y=1 -> V cols [256,512) -> vbuf_t [abh][d][m']
// with per-64 key permutation m' = base64 + (r%16)*4 + r/16.
// ---------------------------------------------------------------------------
__global__ __launch_bounds__(256) void kv_mfma(
    const bf16* __restrict__ xsb, const bf16* __restrict__ wb,
    bf16* __restrict__ kbuf, bf16* __restrict__ vbuf_t) {
  __shared__ bf16 Wl[2][8192];
  const int t = threadIdx.x;
  const int wave = t >> 6, lane = t & 63, quad = lane >> 4, l16 = lane & 15;
  const int row0 = blockIdx.x * 64 + wave * 16;
  const int isV = blockIdx.y;
  const bf16* ap = xsb + (row0 + l16) * 256 + quad * 8;
  const bf16* wbase = wb + WKV_OFF + isV * 65536;   // 256 cols x 256 K
  GEMM256_BODY(ap, wbase, 256);
  #pragma unroll
  for (int j = 0; j < 16; ++j) {
    const int o = j * 16 + l16;          // 0..255 within half
    const int h = o >> 5, d = o & 31;
    #pragma unroll
    for (int r = 0; r < 4; ++r) {
      const int row = row0 + quad * 4 + r;
      const int m = row & 1023;
      const bf16 val = f2b(acc[j][r]);
      if (!isV) {
        kbuf[((row >> 10) * 8 + h) * 32768 + m * 32 + d] = val;
      } else {
        const int rr = m & 63;
        const int mp = (m & ~63) + (rr & 15) * 4 + (rr >> 4);
        vbuf_t[((row >> 10) * 8 + h) * 32768 + d * 1024 + mp] = val;
      }
    }
  }
}

// ---------------------------------------------------------------------------
// Kernel 5: MFMA flash attention, LDS-staged K/V (double-buffered) —
// unchanged from round 12/13/15 (proven).
// ---------------------------------------------------------------------------
__global__ __launch_bounds__(256) void attn_mfma(
    const bf16* __restrict__ q, const bf16* __restrict__ kbuf,
    const bf16* __restrict__ vbuf_t, bf16* __restrict__ att) {
  const int abh = blockIdx.y;
  const int ab = abh >> 3;
  const int h = abh & 7;
  const int t = threadIdx.x;
  const int wave = t >> 6, lane = t & 63, quad = lane >> 4, l16 = lane & 15;
  const int qbase = blockIdx.x * 128 + wave * 32;

  __shared__ bf16 KT[2][2048];
  __shared__ bf16 VT[2][2048];
  __shared__ bf16 P_lds[4][2][16][72];

  const bf16* kb = kbuf + abh * 32768;
  const bf16* vb = vbuf_t + abh * 32768;

  const int kg = (t >> 6) * 512 + ((t >> 2) & 15) * 32 + (t & 3) * 8;
  const int vg_row = (t >> 7) * 16 + ((t >> 3) & 15);
  const int vg_col = ((t >> 2) & 1) * 32 + (t & 3) * 8;

  bf16x8 qf[2];
  #pragma unroll
  for (int s = 0; s < 2; ++s)
    qf[s] = *(const bf16x8*)(
        q + (ab * 4096 + qbase + s * 16 + l16) * 256 + h * 32 + quad * 8);

  {
    const bf16x8 kr = *(const bf16x8*)(kb + kg);
    const bf16x8 vr = *(const bf16x8*)(vb + vg_row * 1024 + vg_col);
    *(bf16x8*)&KT[0][t * 8] = kr;
    *(bf16x8*)&VT[0][t * 8] = vr;
  }
  __syncthreads();

  f32x4 o[2][2];
  float lp[2][4];
  #pragma unroll
  for (int s = 0; s < 2; ++s) {
    o[s][0] = (f32x4){0.f, 0.f, 0.f, 0.f};
    o[s][1] = (f32x4){0.f, 0.f, 0.f, 0.f};
    #pragma unroll
    for (int r = 0; r < 4; ++r) lp[s][r] = 0.0f;
  }
  const f32x4 zero = {0.f, 0.f, 0.f, 0.f};

  for (int kt = 0; kt < 16; ++kt) {
    const int cur = kt & 1;
    bf16x8 kr, vr;
    const bool pf = (kt + 1 < 16);
    if (pf) {
      const int nk0 = (kt + 1) * 64;
      kr = *(const bf16x8*)(kb + nk0 * 32 + kg);
      vr = *(const bf16x8*)(vb + vg_row * 1024 + nk0 + vg_col);
    }
    f32x4 S[2][4];
    #pragma unroll
    for (int tt = 0; tt < 4; ++tt) {
      const bf16x8 kf =
          *(const bf16x8*)&KT[cur][(tt * 64 + l16 * 4 + quad) * 8];
      S[0][tt] = MFMA(qf[0], kf, zero);
      S[1][tt] = MFMA(qf[1], kf, zero);
    }
    #pragma unroll
    for (int s = 0; s < 2; ++s) {
      #pragma unroll
      for (int r = 0; r < 4; ++r) {
        const float p0 = __expf(S[s][0][r]);
        const float p1 = __expf(S[s][1][r]);
        const float p2 = __expf(S[s][2][r]);
        const float p3 = __expf(S[s][3][r]);
        lp[s][r] += (p0 + p1) + (p2 + p3);
        const __hip_bfloat162 lo = __float22bfloat162_rn(float2{p0, p1});
        const __hip_bfloat162 hi = __float22bfloat162_rn(float2{p2, p3});
        union { __hip_bfloat162 h2[2]; short4v sv; } u;
        u.h2[0] = lo; u.h2[1] = hi;
        *(short4v*)&P_lds[wave][s][quad * 4 + r][l16 * 4] = u.sv;
      }
    }
    #pragma unroll
    for (int c2 = 0; c2 < 2; ++c2) {
      const bf16x8 pf0 = *(const bf16x8*)&P_lds[wave][0][l16][c2 * 32 + quad * 8];
      const bf16x8 pf1 = *(const bf16x8*)&P_lds[wave][1][l16][c2 * 32 + quad * 8];
      #pragma unroll
      for (int dh = 0; dh < 2; ++dh) {
        const bf16x8 vf = *(const bf16x8*)&VT[cur]
            [(dh * 128 + l16 * 8 + c2 * 4 + quad) * 8];
        o[0][dh] = MFMA(pf0, vf, o[0][dh]);
        o[1][dh] = MFMA(pf1, vf, o[1][dh]);
      }
    }
    if (pf) {
      *(bf16x8*)&KT[cur ^ 1][t * 8] = kr;
      *(bf16x8*)&VT[cur ^ 1][t * 8] = vr;
    }
    __syncthreads();
  }
  #pragma unroll
  for (int s = 0; s < 2; ++s) {
    #pragma unroll
    for (int r = 0; r < 4; ++r) {
      float li = lp[s][r];
      #pragma unroll
      for (int off = 1; off < 16; off <<= 1) li += __shfl_xor(li, off, 16);
      const float inv = 1.0f / li;
      const int qrow = ab * 4096 + qbase + s * 16 + quad * 4 + r;
      bf16* orow = att + qrow * 256 + h * 32;
      orow[l16]      = f2b(o[s][0][r] * inv);
      orow[16 + l16] = f2b(o[s][1][r] * inv);
    }
  }
}

// ---------------------------------------------------------------------------
// Kernel 6: y = att @ Wproj^T + bproj -> fp32 d_out. Full-width blocks.
// grid 256.
// ---------------------------------------------------------------------------
__global__ __launch_bounds__(256) void proj_mfma(
    const bf16* __restrict__ att, const bf16* __restrict__ wb,
    const float* __restrict__ bp, float* __restrict__ outp) {
  __shared__ bf16 Wl[2][8192];
  const int t = threadIdx.x;
  const int wave = t >> 6, lane = t & 63, quad = lane >> 4, l16 = lane & 15;
  const int row0 = blockIdx.x * 64 + wave * 16;
  const bf16* ap = att + (row0 + l16) * 256 + quad * 8;
  const bf16* wbase = wb + WP_OFF;
  GEMM256_BODY(ap, wbase, 256);
  #pragma unroll
  for (int j = 0; j < 16; ++j) {
    const int col = j * 16 + l16;
    const float bv = bp[col];
    #pragma unroll
    for (int r = 0; r < 4; ++r)
      outp[(row0 + quad * 4 + r) * 256 + col] = acc[j][r] + bv;
  }
}

// ---------------------------------------------------------------------------
extern "C" void kernel_launch(void* const* d_in, const int* in_sizes, int n_in,
                              void* d_out, int out_size, void* d_ws, size_t ws_size,
                              hipStream_t stream) {
  const float* x0    = (const float*)d_in[0];
  const float* x1    = (const float*)d_in[1];
  const float* Wq    = (const float*)d_in[2];
  const float* Wkv   = (const float*)d_in[3];
  const float* Wproj = (const float*)d_in[4];
  const float* bproj = (const float*)d_in[5];
  const float* Wsr   = (const float*)d_in[6];
  const float* bsr   = (const float*)d_in[7];
  const float* lnw0  = (const float*)d_in[8];
  const float* lnb0  = (const float*)d_in[9];
  const float* lnw1  = (const float*)d_in[10];
  const float* lnb1  = (const float*)d_in[11];

  // d_out (16 MB): [q bf16 8 MB][xb bf16 8 MB] -> finally y fp32 16 MB.
  // ws (15 MB): att 8 | xsb 2 | kbuf 2 | vbuf_t 2 | wb 1.
  bf16* q_bf   = (bf16*)d_out;
  bf16* xb     = q_bf + 4194304;
  bf16* att_bf = (bf16*)d_ws;
  bf16* xsb    = att_bf + 4194304;
  bf16* kbuf   = xsb + 1048576;
  bf16* vbuf_t = kbuf + 1048576;
  bf16* wb     = vbuf_t + 1048576;
  float* y     = (float*)d_out;

  const dim3 blk(256);
  cvt_x<<<dim3(1024), blk, 0, stream>>>(x0, x1, xb);
  cvt_w<<<dim3(512), blk, 0, stream>>>(Wq, Wkv, Wproj, Wsr, wb);
  qproj_mfma<<<dim3(256), blk, 0, stream>>>(xb, wb, q_bf);
  conv_mfma<<<dim3(32, 4), blk, 0, stream>>>(xb, wb, bsr, xsb);
  ln_kernel<<<dim3(4096), blk, 0, stream>>>(xsb, lnw0, lnb0, lnw1, lnb1);
  kv_mfma<<<dim3(64, 2), blk, 0, stream>>>(xsb, wb, kbuf, vbuf_t);
  attn_mfma<<<dim3(32, 32), blk, 0, stream>>>(q_bf, kbuf, vbuf_t, att_bf);
  proj_mfma<<<dim3(256), blk, 0, stream>>>(att_bf, wb, bproj, y);
}

// Round 17
// 168.715 us; speedup vs baseline: 1.1214x; 1.1214x over previous
//
#include <hip/hip_runtime.h>
#include <hip/hip_bf16.h>
#include <cstddef>

typedef __hip_bfloat16 bf16;
typedef __attribute__((ext_vector_type(8))) short bf16x8;   // MFMA A/B frag
typedef __attribute__((ext_vector_type(4))) float f32x4;    // MFMA C/D frag
typedef __attribute__((ext_vector_type(4))) short short4v;  // 4x bf16 packed

__device__ __forceinline__ float b2f(bf16 v) { return __bfloat162float(v); }
__device__ __forceinline__ bf16 f2b(float v) { return __float2bfloat16(v); }

#define MFMA(a, b, c) __builtin_amdgcn_mfma_f32_16x16x32_bf16((a), (b), (c), 0, 0, 0)

// Weight layout inside wb (bf16): Wq [0,64K), Wkv [64K,192K), Wp [192K,256K),
// Wsr permuted [256K,512K) with k' = p*256 + c  (p = kh*2+kw).
#define WQ_OFF   0
#define WKV_OFF  65536
#define WP_OFF   196608
#define WSR_OFF  262144

// ---------------------------------------------------------------------------
// Prepass A: x0|x1 fp32 -> xb bf16 (16384 x 256 rows = a*8192 + b*4096 + n).
// ---------------------------------------------------------------------------
__global__ __launch_bounds__(256) void cvt_x(
    const float* __restrict__ x0, const float* __restrict__ x1,
    bf16* __restrict__ xb) {
  const int gid = blockIdx.x * 256 + threadIdx.x;   // 262144 threads
  for (int i = gid; i < 1048576; i += 262144) {     // float4 units
    const float4 v = (i < 524288) ? ((const float4*)x0)[i]
                                  : ((const float4*)x1)[i - 524288];
    union { bf16 h[4]; short4v s; } u;
    u.h[0] = f2b(v.x); u.h[1] = f2b(v.y); u.h[2] = f2b(v.z); u.h[3] = f2b(v.w);
    ((short4v*)xb)[i] = u.s;
  }
}

// ---------------------------------------------------------------------------
// Prepass B: weights fp32 -> wb bf16 (Wsr with the p-major k permutation).
// ---------------------------------------------------------------------------
__global__ __launch_bounds__(256) void cvt_w(
    const float* __restrict__ Wq, const float* __restrict__ Wkv,
    const float* __restrict__ Wp, const float* __restrict__ Wsr,
    bf16* __restrict__ wb) {
  const int gid = blockIdx.x * 256 + threadIdx.x;   // 131072 threads
  for (int i = gid; i < 524288; i += 131072) {
    float v;
    if (i < WKV_OFF)       v = Wq[i];
    else if (i < WP_OFF)   v = Wkv[i - WKV_OFF];
    else if (i < WSR_OFF)  v = Wp[i - WP_OFF];
    else {
      const int r = i - WSR_OFF;
      const int o = r >> 10, k = r & 1023;
      const int p = k >> 8, c = k & 255;
      v = Wsr[o * 1024 + c * 4 + p];
    }
    wb[i] = f2b(v);
  }
}

// W-tile staging helper: 64 rows x 256 K bf16 (32 KB) into LDS [64][264]
// (pad 264 -> 2-way-free bank reads). Coalesced 16 B per thread.
#define STAGE_W(W_lds, wgl, ldg)                                             \
  _Pragma("unroll")                                                          \
  for (int u = 0; u < 8; ++u) {                                              \
    const int idx = u * 256 + t;                                             \
    const int wr = idx >> 5;                                                 \
    const int wc = (idx & 31) * 8;                                           \
    *(bf16x8*)&W_lds[wr][wc] = *(const bf16x8*)((wgl) + wr * (ldg) + wc);    \
  }

// ---------------------------------------------------------------------------
// Kernel 1: q = (xb @ Wq^T) * scale -> bf16 (d_out staging). W tile in LDS;
// block 64 rows x 64 cols (wave = 16 rows). grid (256, 4) = 4 blocks/CU.
// ---------------------------------------------------------------------------
__global__ __launch_bounds__(256) void qproj_mfma(
    const bf16* __restrict__ xb, const bf16* __restrict__ wb,
    bf16* __restrict__ q) {
  __shared__ bf16 W_lds[64][264];
  const int t = threadIdx.x;
  const int wave = t >> 6, lane = t & 63, quad = lane >> 4, l16 = lane & 15;
  const int row0 = blockIdx.x * 64 + wave * 16;
  const int colh = blockIdx.y * 64;
  STAGE_W(W_lds, wb + WQ_OFF + colh * 256, 256);
  __syncthreads();
  const bf16* ap = xb + (row0 + l16) * 256 + quad * 8;
  f32x4 acc[4];
  #pragma unroll
  for (int j = 0; j < 4; ++j) acc[j] = (f32x4){0.f, 0.f, 0.f, 0.f};
  #pragma unroll
  for (int k0 = 0; k0 < 256; k0 += 32) {
    const bf16x8 af = *(const bf16x8*)(ap + k0);
    #pragma unroll
    for (int j = 0; j < 4; ++j) {
      const bf16x8 wf = *(const bf16x8*)&W_lds[j * 16 + l16][k0 + quad * 8];
      acc[j] = MFMA(af, wf, acc[j]);
    }
  }
  const float scale = 0.17677669529663687f;  // 1/sqrt(32)
  #pragma unroll
  for (int j = 0; j < 4; ++j)
    #pragma unroll
    for (int r = 0; r < 4; ++r)
      q[(row0 + quad * 4 + r) * 256 + colh + j * 16 + l16] =
          f2b(acc[j][r] * scale);
}

// ---------------------------------------------------------------------------
// Kernel 2: conv as 4 p-passes of 256-K MFMA GEMM (Wsr pre-permuted).
// W tile (per p) in LDS; block 64 rows x 64 cols. grid (64, 4).
// ---------------------------------------------------------------------------
__global__ __launch_bounds__(256) void conv_mfma(
    const bf16* __restrict__ xb, const bf16* __restrict__ wb,
    const float* __restrict__ bsr, bf16* __restrict__ xsb) {
  __shared__ bf16 W_lds[64][264];
  const int t = threadIdx.x;
  const int wave = t >> 6, lane = t & 63, quad = lane >> 4, l16 = lane & 15;
  const int row0 = blockIdx.x * 64 + wave * 16;
  const int colh = blockIdx.y * 64;
  const int mrow = row0 + l16;
  const int ab = mrow >> 10;
  const int m = mrow & 1023;
  const int mi_ = m >> 5, mj = m & 31;
  f32x4 acc[4];
  #pragma unroll
  for (int j = 0; j < 4; ++j) acc[j] = (f32x4){0.f, 0.f, 0.f, 0.f};
  for (int p = 0; p < 4; ++p) {
    __syncthreads();   // protect previous pass's W_lds reads
    STAGE_W(W_lds, wb + WSR_OFF + colh * 1024 + p * 256, 1024);
    __syncthreads();
    const int n = (2 * mi_ + (p >> 1)) * 64 + 2 * mj + (p & 1);
    const bf16* ap = xb + (ab * 4096 + n) * 256 + quad * 8;
    #pragma unroll
    for (int c0 = 0; c0 < 256; c0 += 32) {
      const bf16x8 af = *(const bf16x8*)(ap + c0);
      #pragma unroll
      for (int j = 0; j < 4; ++j) {
        const bf16x8 wf = *(const bf16x8*)&W_lds[j * 16 + l16][c0 + quad * 8];
        acc[j] = MFMA(af, wf, acc[j]);
      }
    }
  }
  #pragma unroll
  for (int j = 0; j < 4; ++j) {
    const int col = colh + j * 16 + l16;
    const float bv = bsr[col];
    #pragma unroll
    for (int r = 0; r < 4; ++r)
      xsb[(row0 + quad * 4 + r) * 256 + col] = f2b(acc[j][r] + bv);
  }
}

// ---------------------------------------------------------------------------
// Kernel 3: layernorm over C=256, in place on xsb (bf16; math fp32).
// ---------------------------------------------------------------------------
__global__ __launch_bounds__(256) void ln_kernel(
    bf16* __restrict__ xsb,
    const float* __restrict__ w0, const float* __restrict__ b0,
    const float* __restrict__ w1, const float* __restrict__ b1) {
  const int row = blockIdx.x;  // 4096
  const int a = row >> 11;
  const int t = threadIdx.x;
  const float v = b2f(xsb[row * 256 + t]);
  __shared__ float red[4], red2[4];
  float s = v;
  #pragma unroll
  for (int off = 32; off >= 1; off >>= 1) s += __shfl_down(s, off, 64);
  if ((t & 63) == 0) red[t >> 6] = s;
  __syncthreads();
  const float mean = (red[0] + red[1] + red[2] + red[3]) * (1.0f / 256.0f);
  const float dv = v - mean;
  float s2 = dv * dv;
  #pragma unroll
  for (int off = 32; off >= 1; off >>= 1) s2 += __shfl_down(s2, off, 64);
  if ((t & 63) == 0) red2[t >> 6] = s2;
  __syncthreads();
  const float var = (red2[0] + red2[1] + red2[2] + red2[3]) * (1.0f / 256.0f);
  const float* w = a ? w1 : w0;
  const float* bbp = a ? b1 : b0;
  xsb[row * 256 + t] = f2b(dv * rsqrtf(var + 1e-5f) * w[t] + bbp[t]);
}

// ---------------------------------------------------------------------------
// Kernel 4: kv = xsb @ Wkv^T. W tile in LDS; block 64 rows x 64 cols.
// K-half -> kbuf [abh][m][d]; V-half -> vbuf_t [abh][d][m'] (per-64 key
// permutation m' = base64 + (r%16)*4 + r/16). grid (64, 8).
// ---------------------------------------------------------------------------
__global__ __launch_bounds__(256) void kv_mfma(
    const bf16* __restrict__ xsb, const bf16* __restrict__ wb,
    bf16* __restrict__ kbuf, bf16* __restrict__ vbuf_t) {
  __shared__ bf16 W_lds[64][264];
  const int t = threadIdx.x;
  const int wave = t >> 6, lane = t & 63, quad = lane >> 4, l16 = lane & 15;
  const int row0 = blockIdx.x * 64 + wave * 16;
  const int colh = blockIdx.y * 64;     // 0..448 over O=512
  STAGE_W(W_lds, wb + WKV_OFF + colh * 256, 256);
  __syncthreads();
  const bf16* ap = xsb + (row0 + l16) * 256 + quad * 8;
  f32x4 acc[4];
  #pragma unroll
  for (int j = 0; j < 4; ++j) acc[j] = (f32x4){0.f, 0.f, 0.f, 0.f};
  #pragma unroll
  for (int k0 = 0; k0 < 256; k0 += 32) {
    const bf16x8 af = *(const bf16x8*)(ap + k0);
    #pragma unroll
    for (int j = 0; j < 4; ++j) {
      const bf16x8 wf = *(const bf16x8*)&W_lds[j * 16 + l16][k0 + quad * 8];
      acc[j] = MFMA(af, wf, acc[j]);
    }
  }
  #pragma unroll
  for (int j = 0; j < 4; ++j) {
    const int o = colh + j * 16 + l16;   // 0..511
    #pragma unroll
    for (int r = 0; r < 4; ++r) {
      const int row = row0 + quad * 4 + r;
      const int m = row & 1023;
      const bf16 val = f2b(acc[j][r]);
      if (o < 256) {
        const int h = o >> 5, d = o & 31;
        kbuf[((row >> 10) * 8 + h) * 32768 + m * 32 + d] = val;
      } else {
        const int o2 = o - 256;
        const int h = o2 >> 5, d = o2 & 31;
        const int rr = m & 63;
        const int mp = (m & ~63) + (rr & 15) * 4 + (rr >> 4);
        vbuf_t[((row >> 10) * 8 + h) * 32768 + d * 1024 + mp] = val;
      }
    }
  }
}

// ---------------------------------------------------------------------------
// Kernel 5: MFMA flash attention, LDS-staged K/V (double-buffered) —
// unchanged from rounds 12/13/15 (proven).
// ---------------------------------------------------------------------------
__global__ __launch_bounds__(256) void attn_mfma(
    const bf16* __restrict__ q, const bf16* __restrict__ kbuf,
    const bf16* __restrict__ vbuf_t, bf16* __restrict__ att) {
  const int abh = blockIdx.y;
  const int ab = abh >> 3;
  const int h = abh & 7;
  const int t = threadIdx.x;
  const int wave = t >> 6, lane = t & 63, quad = lane >> 4, l16 = lane & 15;
  const int qbase = blockIdx.x * 128 + wave * 32;

  __shared__ bf16 KT[2][2048];
  __shared__ bf16 VT[2][2048];
  __shared__ bf16 P_lds[4][2][16][72];

  const bf16* kb = kbuf + abh * 32768;
  const bf16* vb = vbuf_t + abh * 32768;

  const int kg = (t >> 6) * 512 + ((t >> 2) & 15) * 32 + (t & 3) * 8;
  const int vg_row = (t >> 7) * 16 + ((t >> 3) & 15);
  const int vg_col = ((t >> 2) & 1) * 32 + (t & 3) * 8;

  bf16x8 qf[2];
  #pragma unroll
  for (int s = 0; s < 2; ++s)
    qf[s] = *(const bf16x8*)(
        q + (ab * 4096 + qbase + s * 16 + l16) * 256 + h * 32 + quad * 8);

  {
    const bf16x8 kr = *(const bf16x8*)(kb + kg);
    const bf16x8 vr = *(const bf16x8*)(vb + vg_row * 1024 + vg_col);
    *(bf16x8*)&KT[0][t * 8] = kr;
    *(bf16x8*)&VT[0][t * 8] = vr;
  }
  __syncthreads();

  f32x4 o[2][2];
  float lp[2][4];
  #pragma unroll
  for (int s = 0; s < 2; ++s) {
    o[s][0] = (f32x4){0.f, 0.f, 0.f, 0.f};
    o[s][1] = (f32x4){0.f, 0.f, 0.f, 0.f};
    #pragma unroll
    for (int r = 0; r < 4; ++r) lp[s][r] = 0.0f;
  }
  const f32x4 zero = {0.f, 0.f, 0.f, 0.f};

  for (int kt = 0; kt < 16; ++kt) {
    const int cur = kt & 1;
    bf16x8 kr, vr;
    const bool pf = (kt + 1 < 16);
    if (pf) {
      const int nk0 = (kt + 1) * 64;
      kr = *(const bf16x8*)(kb + nk0 * 32 + kg);
      vr = *(const bf16x8*)(vb + vg_row * 1024 + nk0 + vg_col);
    }
    f32x4 S[2][4];
    #pragma unroll
    for (int tt = 0; tt < 4; ++tt) {
      const bf16x8 kf =
          *(const bf16x8*)&KT[cur][(tt * 64 + l16 * 4 + quad) * 8];
      S[0][tt] = MFMA(qf[0], kf, zero);
      S[1][tt] = MFMA(qf[1], kf, zero);
    }
    #pragma unroll
    for (int s = 0; s < 2; ++s) {
      #pragma unroll
      for (int r = 0; r < 4; ++r) {
        const float p0 = __expf(S[s][0][r]);
        const float p1 = __expf(S[s][1][r]);
        const float p2 = __expf(S[s][2][r]);
        const float p3 = __expf(S[s][3][r]);
        lp[s][r] += (p0 + p1) + (p2 + p3);
        const __hip_bfloat162 lo = __float22bfloat162_rn(float2{p0, p1});
        const __hip_bfloat162 hi = __float22bfloat162_rn(float2{p2, p3});
        union { __hip_bfloat162 h2[2]; short4v sv; } u;
        u.h2[0] = lo; u.h2[1] = hi;
        *(short4v*)&P_lds[wave][s][quad * 4 + r][l16 * 4] = u.sv;
      }
    }
    #pragma unroll
    for (int c2 = 0; c2 < 2; ++c2) {
      const bf16x8 pf0 = *(const bf16x8*)&P_lds[wave][0][l16][c2 * 32 + quad * 8];
      const bf16x8 pf1 = *(const bf16x8*)&P_lds[wave][1][l16][c2 * 32 + quad * 8];
      #pragma unroll
      for (int dh = 0; dh < 2; ++dh) {
        const bf16x8 vf = *(const bf16x8*)&VT[cur]
            [(dh * 128 + l16 * 8 + c2 * 4 + quad) * 8];
        o[0][dh] = MFMA(pf0, vf, o[0][dh]);
        o[1][dh] = MFMA(pf1, vf, o[1][dh]);
      }
    }
    if (pf) {
      *(bf16x8*)&KT[cur ^ 1][t * 8] = kr;
      *(bf16x8*)&VT[cur ^ 1][t * 8] = vr;
    }
    __syncthreads();
  }
  #pragma unroll
  for (int s = 0; s < 2; ++s) {
    #pragma unroll
    for (int r = 0; r < 4; ++r) {
      float li = lp[s][r];
      #pragma unroll
      for (int off = 1; off < 16; off <<= 1) li += __shfl_xor(li, off, 16);
      const float inv = 1.0f / li;
      const int qrow = ab * 4096 + qbase + s * 16 + quad * 4 + r;
      bf16* orow = att + qrow * 256 + h * 32;
      orow[l16]      = f2b(o[s][0][r] * inv);
      orow[16 + l16] = f2b(o[s][1][r] * inv);
    }
  }
}

// ---------------------------------------------------------------------------
// Kernel 6: y = att @ Wproj^T + bproj -> fp32 d_out. W tile in LDS; block
// 64 rows x 64 cols. grid (256, 4).
// ---------------------------------------------------------------------------
__global__ __launch_bounds__(256) void proj_mfma(
    const bf16* __restrict__ att, const bf16* __restrict__ wb,
    const float* __restrict__ bp, float* __restrict__ outp) {
  __shared__ bf16 W_lds[64][264];
  const int t = threadIdx.x;
  const int wave = t >> 6, lane = t & 63, quad = lane >> 4, l16 = lane & 15;
  const int row0 = blockIdx.x * 64 + wave * 16;
  const int colh = blockIdx.y * 64;
  STAGE_W(W_lds, wb + WP_OFF + colh * 256, 256);
  __syncthreads();
  const bf16* ap = att + (row0 + l16) * 256 + quad * 8;
  f32x4 acc[4];
  #pragma unroll
  for (int j = 0; j < 4; ++j) acc[j] = (f32x4){0.f, 0.f, 0.f, 0.f};
  #pragma unroll
  for (int k0 = 0; k0 < 256; k0 += 32) {
    const bf16x8 af = *(const bf16x8*)(ap + k0);
    #pragma unroll
    for (int j = 0; j < 4; ++j) {
      const bf16x8 wf = *(const bf16x8*)&W_lds[j * 16 + l16][k0 + quad * 8];
      acc[j] = MFMA(af, wf, acc[j]);
    }
  }
  #pragma unroll
  for (int j = 0; j < 4; ++j) {
    const int col = colh + j * 16 + l16;
    const float bv = bp[col];
    #pragma unroll
    for (int r = 0; r < 4; ++r)
      outp[(row0 + quad * 4 + r) * 256 + col] = acc[j][r] + bv;
  }
}

// ---------------------------------------------------------------------------
extern "C" void kernel_launch(void* const* d_in, const int* in_sizes, int n_in,
                              void* d_out, int out_size, void* d_ws, size_t ws_size,
                              hipStream_t stream) {
  const float* x0    = (const float*)d_in[0];
  const float* x1    = (const float*)d_in[1];
  const float* Wq    = (const float*)d_in[2];
  const float* Wkv   = (const float*)d_in[3];
  const float* Wproj = (const float*)d_in[4];
  const float* bproj = (const float*)d_in[5];
  const float* Wsr   = (const float*)d_in[6];
  const float* bsr   = (const float*)d_in[7];
  const float* lnw0  = (const float*)d_in[8];
  const float* lnb0  = (const float*)d_in[9];
  const float* lnw1  = (const float*)d_in[10];
  const float* lnb1  = (const float*)d_in[11];

  // d_out (16 MB): [q bf16 8 MB][xb bf16 8 MB] -> finally y fp32 16 MB.
  // ws (15 MB): att 8 | xsb 2 | kbuf 2 | vbuf_t 2 | wb 1.
  bf16* q_bf   = (bf16*)d_out;
  bf16* xb     = q_bf + 4194304;
  bf16* att_bf = (bf16*)d_ws;
  bf16* xsb    = att_bf + 4194304;
  bf16* kbuf   = xsb + 1048576;
  bf16* vbuf_t = kbuf + 1048576;
  bf16* wb     = vbuf_t + 1048576;
  float* y     = (float*)d_out;

  const dim3 blk(256);
  cvt_x<<<dim3(1024), blk, 0, stream>>>(x0, x1, xb);
  cvt_w<<<dim3(512), blk, 0, stream>>>(Wq, Wkv, Wproj, Wsr, wb);
  qproj_mfma<<<dim3(256, 4), blk, 0, stream>>>(xb, wb, q_bf);
  conv_mfma<<<dim3(64, 4), blk, 0, stream>>>(xb, wb, bsr, xsb);
  ln_kernel<<<dim3(4096), blk, 0, stream>>>(xsb, lnw0, lnb0, lnw1, lnb1);
  kv_mfma<<<dim3(64, 8), blk, 0, stream>>>(xsb, wb, kbuf, vbuf_t);
  attn_mfma<<<dim3(32, 32), blk, 0, stream>>>(q_bf, kbuf, vbuf_t, att_bf);
  proj_mfma<<<dim3(256, 4), blk, 0, stream>>>(att_bf, wb, bproj, y);
}